// Round 7
// baseline (8859.117 us; speedup 1.0000x reference)
//
#include <hip/hip_runtime.h>
#include <math.h>

typedef _Float16 f16;
typedef _Float16 f16x8 __attribute__((ext_vector_type(8)));
typedef float f32x4 __attribute__((ext_vector_type(4)));

#define NB 32768
#define NH 512
#define NM 128
#define NIN 640
#define NHID 2048
#define NOUT 642
#define NOUTP 768
#define ITERS 16
#define NBLK 256
// 3-split f16: v = a0 + a1*EPS1 + a2*EPS2,  EPS1=2^-11, EPS2=2^-22
#define S1 2048.0f
#define S2 4194304.0f
#define EPS1 4.8828125e-4f
#define EPS2 2.384185791015625e-7f

__device__ __forceinline__ void gload16(const void* g, void* lds) {
  __builtin_amdgcn_global_load_lds(
      reinterpret_cast<const __attribute__((address_space(1))) unsigned int*>((uintptr_t)g),
      reinterpret_cast<__attribute__((address_space(3))) unsigned int*>((unsigned int)(uintptr_t)lds),
      16, 0, 0);
}

__device__ __forceinline__ f32x4 mfma16(f16x8 a, f16x8 b, f32x4 c) {
  return __builtin_amdgcn_mfma_f32_16x16x32_f16(a, b, c, 0, 0, 0);
}

__device__ __forceinline__ void split3(float v, f16& a0, f16& a1, f16& a2) {
  a0 = (f16)v;
  float r1 = v - (float)a0;
  a1 = (f16)(r1 * S1);
  float r2 = r1 - (float)a1 * EPS1;
  a2 = (f16)(r2 * S2);
}

// grid barrier: all NBLK blocks co-resident (1/CU via LDS). Release fence (L2 wb) before
// arrive, acquire fence (L2 inv) after — required for cross-XCD h1/h2/xm3 visibility.
__device__ __forceinline__ void gsync(int* bar, int target) {
  __syncthreads();
  if (threadIdx.x == 0) {
    __threadfence();
    __hip_atomic_fetch_add(bar, 1, __ATOMIC_RELAXED, __HIP_MEMORY_SCOPE_AGENT);
    while (__hip_atomic_load(bar, __ATOMIC_RELAXED, __HIP_MEMORY_SCOPE_AGENT) < target)
      __builtin_amdgcn_s_sleep(2);
    __threadfence();
  }
  __syncthreads();
}

// ---------------- weight transpose + 3-split: W[K][Nreal] -> WT[n][3][K] ----------------
__global__ void k_prepW(const float* __restrict__ W, f16* __restrict__ WT,
                        int K, int Nreal) {
  __shared__ float tile[32][33];
  int k0 = blockIdx.x * 32, n0 = blockIdx.y * 32;
  int tx = threadIdx.x & 31, ty = threadIdx.x >> 5;
#pragma unroll
  for (int r = 0; r < 4; ++r) {
    int kk = ty + 8 * r;
    int n = n0 + tx;
    tile[kk][tx] = (n < Nreal) ? W[(size_t)(k0 + kk) * Nreal + n] : 0.0f;
  }
  __syncthreads();
#pragma unroll
  for (int r = 0; r < 4; ++r) {
    int nl = ty + 8 * r;
    float v = tile[tx][nl];
    f16 a0, a1, a2; split3(v, a0, a1, a2);
    size_t o = (size_t)(n0 + nl) * (3 * K) + k0 + tx;
    WT[o] = a0; WT[o + K] = a1; WT[o + 2 * K] = a2;
  }
}

// ---------------- split x into merged state xm3[row][3][640] (x cols 0..511) ----------------
__global__ void k_splitX(const float* __restrict__ x, f16* __restrict__ xm3) {
  int i = blockIdx.x * 256 + threadIdx.x;
  int row = i >> 9, c = i & 511;
  f16 a0, a1, a2; split3(x[i], a0, a1, a2);
  size_t o = (size_t)row * (3 * NIN) + c;
  xm3[o] = a0; xm3[o + NIN] = a1; xm3[o + 2 * NIN] = a2;
}

// ---------------- init mem part of xm3 (cols 512..639), fp/list/cnt/bar ----------------
__global__ void k_init(f16* __restrict__ xm3, float* __restrict__ fpb,
                       int* __restrict__ list0, int* __restrict__ cnt) {
  int gid = blockIdx.x * blockDim.x + threadIdx.x;
  if (gid < NB * NM) {
    int row = gid >> 7, c = gid & 127;
    size_t o = (size_t)row * (3 * NIN) + 512 + c;
    xm3[o] = (f16)((c == 0) ? 16.0f : 0.0f);
    xm3[o + NIN] = (f16)0.0f;
    xm3[o + 2 * NIN] = (f16)0.0f;
  }
  if (gid < NB) { fpb[gid] = 0.0f; list0[gid] = gid; }
  if (gid < 64) cnt[gid] = (gid == 0) ? NB : 0;   // counts [0..16], barrier at [32]
}

// ===== GEMM tile: 128x128, BK=32, 8 waves (2x4), wave tile 64x32, 6-pass 3-split =====
// LDS: TRIPLE-buffered 6 planes of [128 rows][32 k] f16, k-slot XOR-swizzled.
// 2-deep pipeline, counted vmcnt(6) per K-step, raw s_barrier (r6-verified).

#define GEMM_PREAMBLE()                                                     \
  int tid = threadIdx.x;                                                    \
  int w = tid >> 6, lane = tid & 63;                                        \
  int wr = w >> 2, wc = w & 3;                                              \
  int arow0 = 16 * w + (lane >> 2);                                         \
  int stg = 512 * w + 8 * lane;                                             \
  int ksrc = (((lane & 3) ^ ((lane >> 3) & 3)) << 3);                       \
  int lm = lane & 15, kb = lane >> 4;                                       \
  int kidx = ((kb ^ ((lm >> 1) & 3)) << 3);                                 \
  int afo[4], bfo[2];                                                       \
  _Pragma("unroll") for (int m = 0; m < 4; ++m)                             \
    afo[m] = (wr * 64 + m * 16 + lm) * 32 + kidx;                           \
  _Pragma("unroll") for (int n = 0; n < 2; ++n)                             \
    bfo[n] = (wc * 32 + n * 16 + lm) * 32 + kidx;                           \
  f32x4 acc0[4][2], acc1[4][2], acc2[4][2];                                 \
  _Pragma("unroll") for (int m = 0; m < 4; ++m)                             \
  _Pragma("unroll") for (int n = 0; n < 2; ++n) {                           \
    acc0[m][n] = (f32x4)0.0f; acc1[m][n] = (f32x4)0.0f;                     \
    acc2[m][n] = (f32x4)0.0f;                                               \
  }

#define GEMM_COMPUTE(BASE)                                                  \
  {                                                                         \
    const f16* _sb = (BASE);                                                \
    f16x8 fa0[4], fa1[4], fa2[4], fb0[2], fb1[2], fb2[2];                   \
    _Pragma("unroll") for (int m = 0; m < 4; ++m) {                         \
      fa0[m] = *(const f16x8*)&_sb[afo[m]];                                 \
      fa1[m] = *(const f16x8*)&_sb[4096 + afo[m]];                          \
      fa2[m] = *(const f16x8*)&_sb[8192 + afo[m]];                          \
    }                                                                       \
    _Pragma("unroll") for (int n = 0; n < 2; ++n) {                         \
      fb0[n] = *(const f16x8*)&_sb[12288 + bfo[n]];                         \
      fb1[n] = *(const f16x8*)&_sb[16384 + bfo[n]];                         \
      fb2[n] = *(const f16x8*)&_sb[20480 + bfo[n]];                         \
    }                                                                       \
    __builtin_amdgcn_s_setprio(1);                                          \
    _Pragma("unroll") for (int m = 0; m < 4; ++m)                           \
    _Pragma("unroll") for (int n = 0; n < 2; ++n) {                         \
      acc0[m][n] = mfma16(fa0[m], fb0[n], acc0[m][n]);                      \
      acc1[m][n] = mfma16(fa0[m], fb1[n], acc1[m][n]);                      \
      acc1[m][n] = mfma16(fa1[m], fb0[n], acc1[m][n]);                      \
      acc2[m][n] = mfma16(fa1[m], fb1[n], acc2[m][n]);                      \
      acc2[m][n] = mfma16(fa0[m], fb2[n], acc2[m][n]);                      \
      acc2[m][n] = mfma16(fa2[m], fb0[n], acc2[m][n]);                      \
    }                                                                       \
    __builtin_amdgcn_s_setprio(0);                                          \
  }

#define STAGE6(K0, DST, PSTRIDE_A, PSTRIDE_B)                               \
  {                                                                         \
    _Pragma("unroll") for (int s = 0; s < 3; ++s) {                         \
      gload16(pA + s * (PSTRIDE_A) + (K0), (DST) + s * 4096 + stg);         \
      gload16(pB + s * (PSTRIDE_B) + (K0), (DST) + (3 + s) * 4096 + stg);   \
    }                                                                       \
  }

#define VMW6() asm volatile("s_waitcnt vmcnt(6)" ::: "memory")
#define VMW0() asm volatile("s_waitcnt vmcnt(0)" ::: "memory")

// NOTE: leading __syncthreads protects SB reuse across consecutive items (persistent loop).
#define GEMM_PIPELOOP(KTOT, PSTRIDE_A, PSTRIDE_B)                           \
  __syncthreads();                                                          \
  STAGE6(0, &SB[0], PSTRIDE_A, PSTRIDE_B);                                  \
  STAGE6(32, &SB[24576], PSTRIDE_A, PSTRIDE_B);                             \
  {                                                                         \
    int cur_off = 0;                                                        \
    for (int k0 = 0; k0 < (KTOT); k0 += 32) {                               \
      if (k0 + 32 < (KTOT)) { VMW6(); } else { VMW0(); }                    \
      __builtin_amdgcn_sched_barrier(0);                                    \
      __builtin_amdgcn_s_barrier();                                         \
      __builtin_amdgcn_sched_barrier(0);                                    \
      int nxt_off = cur_off + 49152; if (nxt_off >= 73728) nxt_off -= 73728;\
      if (k0 + 64 < (KTOT)) { f16* nb = &SB[nxt_off];                       \
        STAGE6(k0 + 64, nb, PSTRIDE_A, PSTRIDE_B); }                        \
      GEMM_COMPUTE(&SB[cur_off]);                                           \
      cur_off += 24576; if (cur_off >= 73728) cur_off -= 73728;             \
    }                                                                       \
  }

#define COMBINE(m, n, q) (acc0[m][n][q] + EPS1 * acc1[m][n][q] + EPS2 * acc2[m][n][q])

// ---------------- tile: layer 1 ----------------
__device__ __forceinline__ void tile_l1(f16* SB,
    const f16* __restrict__ xm3, const f16* __restrict__ WT,
    const float* __restrict__ b1, f16* __restrict__ h1,
    const int* __restrict__ list, int cnt, int chunk_off, int lm0, int n0, int lim) {
  GEMM_PREAMBLE();
  int pu = chunk_off + lm0 + arow0;
  int idx = list[pu < cnt ? pu : (cnt - 1)];
  const f16* pA = xm3 + (size_t)idx * (3 * NIN) + ksrc;
  const f16* pB = WT + (size_t)(n0 + arow0) * (3 * NIN) + ksrc;
  GEMM_PIPELOOP(NIN, NIN, NIN);
#pragma unroll
  for (int n = 0; n < 2; ++n) {
    int col = n0 + wc * 32 + n * 16 + lm;
    float bb = b1[col];
#pragma unroll
    for (int m = 0; m < 4; ++m) {
#pragma unroll
      for (int q = 0; q < 4; ++q) {
        int gr = lm0 + wr * 64 + m * 16 + kb * 4 + q;
        if (gr < lim) {
          float v = fmaxf(COMBINE(m, n, q) + bb, 0.0f);
          f16 a0, a1, a2; split3(v, a0, a1, a2);
          size_t o = (size_t)gr * (3 * NHID) + col;
          h1[o] = a0; h1[o + NHID] = a1; h1[o + 2 * NHID] = a2;
        }
      }
    }
  }
}

// ---------------- tile: layer 2 ----------------
__device__ __forceinline__ void tile_l2(f16* SB,
    const f16* __restrict__ h1, const f16* __restrict__ WT,
    const float* __restrict__ b2, f16* __restrict__ h2,
    int lm0, int n0, int lim) {
  GEMM_PREAMBLE();
  const f16* pA = h1 + (size_t)(lm0 + arow0) * (3 * NHID) + ksrc;
  const f16* pB = WT + (size_t)(n0 + arow0) * (3 * NHID) + ksrc;
  GEMM_PIPELOOP(NHID, NHID, NHID);
#pragma unroll
  for (int n = 0; n < 2; ++n) {
    int col = n0 + wc * 32 + n * 16 + lm;
    float bb = b2[col];
#pragma unroll
    for (int m = 0; m < 4; ++m) {
#pragma unroll
      for (int q = 0; q < 4; ++q) {
        int gr = lm0 + wr * 64 + m * 16 + kb * 4 + q;
        if (gr < lim) {
          float v = fmaxf(COMBINE(m, n, q) + bb, 0.0f);
          f16 a0, a1, a2; split3(v, a0, a1, a2);
          size_t o = (size_t)gr * (3 * NHID) + col;
          h2[o] = a0; h2[o + NHID] = a1; h2[o + 2 * NHID] = a2;
        }
      }
    }
  }
}

// ---------------- tile: layer 3 ----------------
__device__ __forceinline__ void tile_l3(f16* SB,
    const f16* __restrict__ h2, const f16* __restrict__ WT,
    const float* __restrict__ b3, f16* __restrict__ xm3,
    float* __restrict__ probs, float* __restrict__ hv,
    const int* __restrict__ list, int cnt, int chunk_off, int lm0, int n0, int lim) {
  GEMM_PREAMBLE();
  const f16* pA = h2 + (size_t)(lm0 + arow0) * (3 * NHID) + ksrc;
  const f16* pB = WT + (size_t)(n0 + arow0) * (3 * NHID) + ksrc;
  GEMM_PIPELOOP(NHID, NHID, NHID);
  float bb[2]; int colv[2];
#pragma unroll
  for (int n = 0; n < 2; ++n) {
    colv[n] = n0 + wc * 32 + n * 16 + lm;
    bb[n] = (colv[n] < NOUT) ? b3[colv[n]] : 0.0f;
  }
#pragma unroll
  for (int m = 0; m < 4; ++m) {
#pragma unroll
    for (int q = 0; q < 4; ++q) {
      int gr = lm0 + wr * 64 + m * 16 + kb * 4 + q;
      if (gr >= lim) continue;
      int r = list[chunk_off + gr];
#pragma unroll
      for (int n = 0; n < 2; ++n) {
        int col = colv[n];
        if (col >= NOUT) continue;
        float v = COMBINE(m, n, q) + bb[n];
        if (col == 0) {
          probs[r] = v;
        } else if (col == 1) {
          hv[r] = v;
        } else if (col < 2 + NH) {
          f16 a0, a1, a2; split3(v, a0, a1, a2);
          size_t o = (size_t)r * (3 * NIN) + (col - 2);
          xm3[o] = a0; xm3[o + NIN] = a1; xm3[o + 2 * NIN] = a2;
        } else {
          f16 a0, a1, a2; split3(v, a0, a1, a2);
          size_t o = (size_t)r * (3 * NIN) + 512 + (col - 2 - NH);
          xm3[o] = a0; xm3[o + NIN] = a1; xm3[o + 2 * NIN] = a2;
        }
      }
    }
  }
}

// ---------------- persistent kernel: all 16 iterations, grid-synced phases ----------------
__global__ __launch_bounds__(512) void k_persist(
    f16* __restrict__ xm3, const f16* __restrict__ W1T, const f16* __restrict__ W2T,
    const f16* __restrict__ W3T, const float* __restrict__ b1,
    const float* __restrict__ b2, const float* __restrict__ b3,
    f16* __restrict__ h1, f16* __restrict__ h2,
    float* __restrict__ probs, float* __restrict__ hv, float* __restrict__ fpb,
    int* __restrict__ list0, int* __restrict__ list1,
    int* __restrict__ cntbuf, int* __restrict__ bar,
    float* __restrict__ out, int CH) {
  __shared__ f16 SB[3 * 6 * 4096];
  int bid = blockIdx.x;
  int bt = 0;

  for (int t = 0; t < ITERS; ++t) {
    int cnt = cntbuf[t];
    const int* lc = (t & 1) ? list1 : list0;
    int* ln       = (t & 1) ? list0 : list1;
    int* cn       = cntbuf + t + 1;
    int nch = (cnt + CH - 1) / CH;
    for (int c = 0; c < nch; ++c) {
      int chunk_off = c * CH;
      int rows = cnt - chunk_off; if (rows > CH) rows = CH;
      int ntiles = (rows + 127) >> 7;
      for (int it = bid; it < ntiles * 16; it += NBLK) {
        int ny = it / ntiles, tx = it - ny * ntiles;
        tile_l1(SB, xm3, W1T, b1, h1, lc, cnt, chunk_off, tx * 128, ny * 128, rows);
      }
      bt += NBLK; gsync(bar, bt);
      for (int it = bid; it < ntiles * 16; it += NBLK) {
        int ny = it / ntiles, tx = it - ny * ntiles;
        tile_l2(SB, h1, W2T, b2, h2, tx * 128, ny * 128, rows);
      }
      bt += NBLK; gsync(bar, bt);
      for (int it = bid; it < ntiles * 6; it += NBLK) {
        int ny = it / ntiles, tx = it - ny * ntiles;
        tile_l3(SB, h2, W3T, b3, xm3, probs, hv, lc, cnt, chunk_off, tx * 128, ny * 128, rows);
      }
      bt += NBLK; gsync(bar, bt);
    }
    // halt update + compaction
    int gtid = bid * 512 + threadIdx.x;
    for (int i = gtid; i < cnt; i += NBLK * 512) {
      int r = lc[i];
      if (hv[r] > 0.0f) {
        fpb[r] = probs[r];
      } else {
        int pos = __hip_atomic_fetch_add(cn, 1, __ATOMIC_RELAXED, __HIP_MEMORY_SCOPE_AGENT);
        ln[pos] = r;
      }
    }
    bt += NBLK; gsync(bar, bt);
  }

  int gtid = bid * 512 + threadIdx.x;
  for (int i = gtid; i < NB; i += NBLK * 512) {
    out[i] = 1.0f / (1.0f + expf(-fpb[i]));
    out[NB + i] = 0.0f;
  }
}

extern "C" void kernel_launch(void* const* d_in, const int* in_sizes, int n_in,
                              void* d_out, int out_size, void* d_ws, size_t ws_size,
                              hipStream_t stream) {
  const float* x  = (const float*)d_in[0];
  const float* W1 = (const float*)d_in[1];
  const float* b1 = (const float*)d_in[2];
  const float* W2 = (const float*)d_in[3];
  const float* b2 = (const float*)d_in[4];
  const float* W3 = (const float*)d_in[5];
  const float* b3 = (const float*)d_in[6];
  float* out = (float*)d_out;

  char* p = (char*)d_ws;
  auto alloc = [&](size_t bytes) {
    char* r = p;
    p += (bytes + 255) & ~(size_t)255;
    return r;
  };
  f16* xm3  = (f16*)alloc((size_t)NB * 3 * NIN * 2);     // 120 MiB
  f16* W1T  = (f16*)alloc((size_t)NHID * 3 * NIN * 2);   // 7.5 MiB
  f16* W2T  = (f16*)alloc((size_t)NHID * 3 * NHID * 2);  // 24 MiB
  f16* W3T  = (f16*)alloc((size_t)NOUTP * 3 * NHID * 2); // 9 MiB
  float* probs = (float*)alloc((size_t)NB * 4);
  float* hvb   = (float*)alloc((size_t)NB * 4);
  float* fpb   = (float*)alloc((size_t)NB * 4);
  int* list0   = (int*)alloc((size_t)NB * 4);
  int* list1   = (int*)alloc((size_t)NB * 4);
  int* cnt     = (int*)alloc(64 * 4);                    // counts [0..16], barrier [32]

  size_t used = (size_t)(p - (char*)d_ws);
  size_t remain = (ws_size > used) ? (ws_size - used) : 0;
  long long chl = (long long)(remain / ((size_t)2 * 3 * NHID * 2)); // h1+h2 = 24576 B/row
  int CH = (int)(chl > NB ? NB : chl);
  CH &= ~127;
  if (CH < 128) CH = 128;
  f16* h1 = (f16*)alloc((size_t)CH * 3 * NHID * 2);
  f16* h2 = (f16*)alloc((size_t)CH * 3 * NHID * 2);

  k_prepW<<<dim3(NIN / 32, NHID / 32), 256, 0, stream>>>(W1, W1T, NIN, NHID);
  k_prepW<<<dim3(NHID / 32, NHID / 32), 256, 0, stream>>>(W2, W2T, NHID, NHID);
  k_prepW<<<dim3(NHID / 32, NOUTP / 32), 256, 0, stream>>>(W3, W3T, NHID, NOUT);
  k_splitX<<<(NB * NH) / 256, 256, 0, stream>>>(x, xm3);
  k_init<<<(NB * NM) / 256, 256, 0, stream>>>(xm3, fpb, list0, cnt);

  k_persist<<<NBLK, 512, 0, stream>>>(xm3, W1T, W2T, W3T, b1, b2, b3,
                                      h1, h2, probs, hvb, fpb,
                                      list0, list1, cnt, cnt + 32, out, CH);
}

// Round 8
// 7432.512 us; speedup vs baseline: 1.1919x; 1.1919x over previous
//
#include <hip/hip_runtime.h>
#include <math.h>

typedef _Float16 f16;
typedef _Float16 f16x8 __attribute__((ext_vector_type(8)));
typedef float f32x4 __attribute__((ext_vector_type(4)));

#define NB 32768
#define NH 512
#define NM 128
#define NIN 640
#define NHID 2048
#define NOUT 642
#define NOUTP 768
#define ITERS 16
// 3-split f16: v = a0 + a1*EPS1 + a2*EPS2,  EPS1=2^-11, EPS2=2^-22
#define S1 2048.0f
#define S2 4194304.0f
#define EPS1 4.8828125e-4f
#define EPS2 2.384185791015625e-7f

__device__ __forceinline__ void gload16(const void* g, void* lds) {
  __builtin_amdgcn_global_load_lds(
      reinterpret_cast<const __attribute__((address_space(1))) unsigned int*>((uintptr_t)g),
      reinterpret_cast<__attribute__((address_space(3))) unsigned int*>((unsigned int)(uintptr_t)lds),
      16, 0, 0);
}

__device__ __forceinline__ f32x4 mfma16(f16x8 a, f16x8 b, f32x4 c) {
  return __builtin_amdgcn_mfma_f32_16x16x32_f16(a, b, c, 0, 0, 0);
}

__device__ __forceinline__ void split3(float v, f16& a0, f16& a1, f16& a2) {
  a0 = (f16)v;
  float r1 = v - (float)a0;
  a1 = (f16)(r1 * S1);
  float r2 = r1 - (float)a1 * EPS1;
  a2 = (f16)(r2 * S2);
}

// ---------------- weight transpose + 3-split: W[K][Nreal] -> WT[n][3][K] ----------------
__global__ void k_prepW(const float* __restrict__ W, f16* __restrict__ WT,
                        int K, int Nreal) {
  __shared__ float tile[32][33];
  int k0 = blockIdx.x * 32, n0 = blockIdx.y * 32;
  int tx = threadIdx.x & 31, ty = threadIdx.x >> 5;
#pragma unroll
  for (int r = 0; r < 4; ++r) {
    int kk = ty + 8 * r;
    int n = n0 + tx;
    tile[kk][tx] = (n < Nreal) ? W[(size_t)(k0 + kk) * Nreal + n] : 0.0f;
  }
  __syncthreads();
#pragma unroll
  for (int r = 0; r < 4; ++r) {
    int nl = ty + 8 * r;
    float v = tile[tx][nl];
    f16 a0, a1, a2; split3(v, a0, a1, a2);
    size_t o = (size_t)(n0 + nl) * (3 * K) + k0 + tx;
    WT[o] = a0; WT[o + K] = a1; WT[o + 2 * K] = a2;
  }
}

// ---------------- split x into merged state xm3[row][3][640] (x cols 0..511) ----------------
__global__ void k_splitX(const float* __restrict__ x, f16* __restrict__ xm3) {
  int i = blockIdx.x * 256 + threadIdx.x;
  int row = i >> 9, c = i & 511;
  f16 a0, a1, a2; split3(x[i], a0, a1, a2);
  size_t o = (size_t)row * (3 * NIN) + c;
  xm3[o] = a0; xm3[o + NIN] = a1; xm3[o + 2 * NIN] = a2;
}

// ---------------- init mem part of xm3 (cols 512..639), fp/list/cnt ----------------
__global__ void k_init(f16* __restrict__ xm3, float* __restrict__ fpb,
                       int* __restrict__ list0, int* __restrict__ cnt) {
  int gid = blockIdx.x * blockDim.x + threadIdx.x;
  if (gid < NB * NM) {
    int row = gid >> 7, c = gid & 127;
    size_t o = (size_t)row * (3 * NIN) + 512 + c;
    xm3[o] = (f16)((c == 0) ? 16.0f : 0.0f);
    xm3[o + NIN] = (f16)0.0f;
    xm3[o + 2 * NIN] = (f16)0.0f;
  }
  if (gid < NB) { fpb[gid] = 0.0f; list0[gid] = gid; }
  if (gid < 32) cnt[gid] = (gid == 0) ? NB : 0;
}

// ===== GEMM: 64x128 tile, BK=32, 256 thr = 4 waves, wave tile 64x32, 6-pass 3-split =====
// LDS: DOUBLE-buffered; per buffer: A planes 64x32 @ {0,2048,4096}, B planes 128x32 @
// {6144,10240,14336} (f16 units). Buffer stride 18432 f16; total 72 KB -> 2 blocks/CU.
// k-slot XOR-swizzle (r7 counter: 0 bank conflicts) via pre-swizzled global source.

#define GEMM_PREAMBLE()                                                     \
  int tid = threadIdx.x;                                                    \
  int w = tid >> 6, lane = tid & 63;                                        \
  int lm = lane & 15, kb = lane >> 4;                                       \
  int kidx = ((kb ^ ((lm >> 1) & 3)) << 3);                                 \
  int ksrc = (((tid & 3) ^ ((tid >> 3) & 3)) << 3);                         \
  int stg = tid * 8;                                                        \
  int afo[4], bfo[2];                                                       \
  _Pragma("unroll") for (int m = 0; m < 4; ++m)                             \
    afo[m] = (m * 16 + lm) * 32 + kidx;                                     \
  _Pragma("unroll") for (int n = 0; n < 2; ++n)                             \
    bfo[n] = (w * 32 + n * 16 + lm) * 32 + kidx + 6144;                     \
  f32x4 acc0[4][2], acc1[4][2], acc2[4][2];                                 \
  _Pragma("unroll") for (int m = 0; m < 4; ++m)                             \
  _Pragma("unroll") for (int n = 0; n < 2; ++n) {                           \
    acc0[m][n] = (f32x4)0.0f; acc1[m][n] = (f32x4)0.0f;                     \
    acc2[m][n] = (f32x4)0.0f;                                               \
  }

#define GEMM_COMPUTE(BASE)                                                  \
  {                                                                         \
    const f16* _sb = (BASE);                                                \
    f16x8 fa0[4], fa1[4], fa2[4], fb0[2], fb1[2], fb2[2];                   \
    _Pragma("unroll") for (int m = 0; m < 4; ++m) {                         \
      fa0[m] = *(const f16x8*)&_sb[afo[m]];                                 \
      fa1[m] = *(const f16x8*)&_sb[2048 + afo[m]];                          \
      fa2[m] = *(const f16x8*)&_sb[4096 + afo[m]];                          \
    }                                                                       \
    _Pragma("unroll") for (int n = 0; n < 2; ++n) {                         \
      fb0[n] = *(const f16x8*)&_sb[bfo[n]];                                 \
      fb1[n] = *(const f16x8*)&_sb[4096 + bfo[n]];                          \
      fb2[n] = *(const f16x8*)&_sb[8192 + bfo[n]];                          \
    }                                                                       \
    __builtin_amdgcn_s_setprio(1);                                          \
    _Pragma("unroll") for (int m = 0; m < 4; ++m)                           \
    _Pragma("unroll") for (int n = 0; n < 2; ++n) {                         \
      acc0[m][n] = mfma16(fa0[m], fb0[n], acc0[m][n]);                      \
      acc1[m][n] = mfma16(fa0[m], fb1[n], acc1[m][n]);                      \
      acc1[m][n] = mfma16(fa1[m], fb0[n], acc1[m][n]);                      \
      acc2[m][n] = mfma16(fa1[m], fb1[n], acc2[m][n]);                      \
      acc2[m][n] = mfma16(fa0[m], fb2[n], acc2[m][n]);                      \
      acc2[m][n] = mfma16(fa2[m], fb0[n], acc2[m][n]);                      \
    }                                                                       \
    __builtin_amdgcn_s_setprio(0);                                          \
  }

// stage one 32-k step: A 3 planes (1 sweep each) + B 3 planes (2 sweeps each) = 9 loads/thread
#define STAGE9(K0, DST, PSA, PSB)                                           \
  {                                                                         \
    _Pragma("unroll") for (int s = 0; s < 3; ++s)                           \
      gload16(pA + s * (PSA) + (K0), (DST) + s * 2048 + stg);               \
    _Pragma("unroll") for (int s = 0; s < 3; ++s) {                         \
      gload16(pB + s * (PSB) + (K0), (DST) + 6144 + s * 4096 + stg);        \
      gload16(pB2 + s * (PSB) + (K0), (DST) + 8192 + s * 4096 + stg);       \
    }                                                                       \
  }

#define GEMM_PIPELOOP(KTOT, PSA, PSB)                                       \
  STAGE9(0, &SB[0], PSA, PSB);                                              \
  __syncthreads();                                                          \
  {                                                                         \
    int pb = 0;                                                             \
    for (int k0 = 0; k0 < (KTOT); k0 += 32, pb ^= 1) {                      \
      if (k0 + 32 < (KTOT))                                                 \
        STAGE9(k0 + 32, pb ? &SB[0] : &SB[18432], PSA, PSB);                \
      GEMM_COMPUTE(pb ? &SB[18432] : &SB[0]);                               \
      __syncthreads();                                                      \
    }                                                                       \
  }

#define COMBINE(m, n, q) (acc0[m][n][q] + EPS1 * acc1[m][n][q] + EPS2 * acc2[m][n][q])

// XCD-affine swizzle for 16 col-tiles: ny = (id&7) + 8*bit3 -> each XCD owns 2 weight panels
#define MAP16(ID, BX, NY) int NY = ((ID) & 7) + 8 * (((ID) >> 3) & 1); int BX = (ID) >> 4;

// ---------------- layer 1: gather xm3 @ W1T, relu+b1 -> h1 (3-split) ----------------
__global__ __launch_bounds__(256, 2) void k_l1(
    const f16* __restrict__ xm3, const f16* __restrict__ WT,
    const float* __restrict__ b1, f16* __restrict__ h1,
    const int* __restrict__ list, const int* __restrict__ cntp,
    int chunk_off, int chunk_rows) {
  int cnt = *cntp;
  MAP16(blockIdx.x, bx, ny);
  int lm0 = bx * 64;
  if (chunk_off + lm0 >= cnt) return;
  int lim = cnt - chunk_off; if (lim > chunk_rows) lim = chunk_rows;
  int n0 = ny * 128;

  __shared__ f16 SB[2 * 18432];
  GEMM_PREAMBLE();

  int pu = chunk_off + lm0 + (tid >> 2);
  int idx = list[pu < cnt ? pu : (cnt - 1)];
  const f16* pA = xm3 + (size_t)idx * (3 * NIN) + ksrc;
  const f16* pB = WT + (size_t)(n0 + (tid >> 2)) * (3 * NIN) + ksrc;
  const f16* pB2 = pB + (size_t)64 * (3 * NIN);

  GEMM_PIPELOOP(NIN, NIN, NIN);

#pragma unroll
  for (int n = 0; n < 2; ++n) {
    int col = n0 + w * 32 + n * 16 + lm;
    float bb = b1[col];
#pragma unroll
    for (int m = 0; m < 4; ++m) {
#pragma unroll
      for (int q = 0; q < 4; ++q) {
        int gr = lm0 + m * 16 + kb * 4 + q;
        if (gr < lim) {
          float v = fmaxf(COMBINE(m, n, q) + bb, 0.0f);
          f16 a0, a1, a2; split3(v, a0, a1, a2);
          size_t o = (size_t)gr * (3 * NHID) + col;
          h1[o] = a0; h1[o + NHID] = a1; h1[o + 2 * NHID] = a2;
        }
      }
    }
  }
}

// ---------------- layer 2: h1 @ W2T, relu+b2 -> h2 (3-split) ----------------
__global__ __launch_bounds__(256, 2) void k_l2(
    const f16* __restrict__ h1, const f16* __restrict__ WT,
    const float* __restrict__ b2, f16* __restrict__ h2,
    const int* __restrict__ cntp, int chunk_off, int chunk_rows) {
  int cnt = *cntp;
  MAP16(blockIdx.x, bx, ny);
  int lm0 = bx * 64;
  if (chunk_off + lm0 >= cnt) return;
  int lim = cnt - chunk_off; if (lim > chunk_rows) lim = chunk_rows;
  int n0 = ny * 128;

  __shared__ f16 SB[2 * 18432];
  GEMM_PREAMBLE();

  const f16* pA = h1 + (size_t)(lm0 + (tid >> 2)) * (3 * NHID) + ksrc;
  const f16* pB = WT + (size_t)(n0 + (tid >> 2)) * (3 * NHID) + ksrc;
  const f16* pB2 = pB + (size_t)64 * (3 * NHID);

  GEMM_PIPELOOP(NHID, NHID, NHID);

#pragma unroll
  for (int n = 0; n < 2; ++n) {
    int col = n0 + w * 32 + n * 16 + lm;
    float bb = b2[col];
#pragma unroll
    for (int m = 0; m < 4; ++m) {
#pragma unroll
      for (int q = 0; q < 4; ++q) {
        int gr = lm0 + m * 16 + kb * 4 + q;
        if (gr < lim) {
          float v = fmaxf(COMBINE(m, n, q) + bb, 0.0f);
          f16 a0, a1, a2; split3(v, a0, a1, a2);
          size_t o = (size_t)gr * (3 * NHID) + col;
          h2[o] = a0; h2[o + NHID] = a1; h2[o + 2 * NHID] = a2;
        }
      }
    }
  }
}

// ---------------- layer 3: h2 @ W3T + b3 -> scatter probs/hv/xm3 ----------------
__global__ __launch_bounds__(256, 2) void k_l3(
    const f16* __restrict__ h2, const f16* __restrict__ WT,
    const float* __restrict__ b3, f16* __restrict__ xm3,
    float* __restrict__ probs, float* __restrict__ hv,
    const int* __restrict__ list, const int* __restrict__ cntp,
    int chunk_off, int chunk_rows) {
  int cnt = *cntp;
  int id = blockIdx.x;
  int bx = id / 6, ny = id - bx * 6;
  int lm0 = bx * 64;
  if (chunk_off + lm0 >= cnt) return;
  int lim = cnt - chunk_off; if (lim > chunk_rows) lim = chunk_rows;
  int n0 = ny * 128;

  __shared__ f16 SB[2 * 18432];
  GEMM_PREAMBLE();

  const f16* pA = h2 + (size_t)(lm0 + (tid >> 2)) * (3 * NHID) + ksrc;
  const f16* pB = WT + (size_t)(n0 + (tid >> 2)) * (3 * NHID) + ksrc;
  const f16* pB2 = pB + (size_t)64 * (3 * NHID);

  GEMM_PIPELOOP(NHID, NHID, NHID);

  float bb[2]; int colv[2];
#pragma unroll
  for (int n = 0; n < 2; ++n) {
    colv[n] = n0 + w * 32 + n * 16 + lm;
    bb[n] = (colv[n] < NOUT) ? b3[colv[n]] : 0.0f;
  }
#pragma unroll
  for (int m = 0; m < 4; ++m) {
#pragma unroll
    for (int q = 0; q < 4; ++q) {
      int gr = lm0 + m * 16 + kb * 4 + q;
      if (gr >= lim) continue;
      int r = list[chunk_off + gr];
#pragma unroll
      for (int n = 0; n < 2; ++n) {
        int col = colv[n];
        if (col >= NOUT) continue;
        float v = COMBINE(m, n, q) + bb[n];
        if (col == 0) {
          probs[r] = v;
        } else if (col == 1) {
          hv[r] = v;
        } else if (col < 2 + NH) {
          f16 a0, a1, a2; split3(v, a0, a1, a2);
          size_t o = (size_t)r * (3 * NIN) + (col - 2);
          xm3[o] = a0; xm3[o + NIN] = a1; xm3[o + 2 * NIN] = a2;
        } else {
          f16 a0, a1, a2; split3(v, a0, a1, a2);
          size_t o = (size_t)r * (3 * NIN) + 512 + (col - 2 - NH);
          xm3[o] = a0; xm3[o + NIN] = a1; xm3[o + 2 * NIN] = a2;
        }
      }
    }
  }
}

// ---------------- halt update + compaction ----------------
__global__ void k_update(const int* __restrict__ listc, int* __restrict__ listn,
                         const float* __restrict__ hv, const float* __restrict__ probs,
                         float* __restrict__ fpb, const int* __restrict__ cntc,
                         int* __restrict__ cntn) {
  int i = blockIdx.x * blockDim.x + threadIdx.x;
  if (i >= *cntc) return;
  int r = listc[i];
  if (hv[r] > 0.0f) {
    fpb[r] = probs[r];
  } else {
    int pos = atomicAdd(cntn, 1);
    listn[pos] = r;
  }
}

// ---------------- final ----------------
__global__ void k_final(const float* __restrict__ fpb, float* __restrict__ out) {
  int i = blockIdx.x * blockDim.x + threadIdx.x;
  if (i < NB) {
    out[i] = 1.0f / (1.0f + expf(-fpb[i]));
    out[NB + i] = 0.0f;
  }
}

extern "C" void kernel_launch(void* const* d_in, const int* in_sizes, int n_in,
                              void* d_out, int out_size, void* d_ws, size_t ws_size,
                              hipStream_t stream) {
  const float* x  = (const float*)d_in[0];
  const float* W1 = (const float*)d_in[1];
  const float* b1 = (const float*)d_in[2];
  const float* W2 = (const float*)d_in[3];
  const float* b2 = (const float*)d_in[4];
  const float* W3 = (const float*)d_in[5];
  const float* b3 = (const float*)d_in[6];
  float* out = (float*)d_out;

  char* p = (char*)d_ws;
  auto alloc = [&](size_t bytes) {
    char* r = p;
    p += (bytes + 255) & ~(size_t)255;
    return r;
  };
  f16* xm3  = (f16*)alloc((size_t)NB * 3 * NIN * 2);     // 120 MiB
  f16* W1T  = (f16*)alloc((size_t)NHID * 3 * NIN * 2);   // 7.5 MiB
  f16* W2T  = (f16*)alloc((size_t)NHID * 3 * NHID * 2);  // 24 MiB
  f16* W3T  = (f16*)alloc((size_t)NOUTP * 3 * NHID * 2); // 9 MiB
  float* probs = (float*)alloc((size_t)NB * 4);
  float* hvb   = (float*)alloc((size_t)NB * 4);
  float* fpb   = (float*)alloc((size_t)NB * 4);
  int* list0   = (int*)alloc((size_t)NB * 4);
  int* list1   = (int*)alloc((size_t)NB * 4);
  int* cnt     = (int*)alloc(32 * 4);

  size_t used = (size_t)(p - (char*)d_ws);
  size_t remain = (ws_size > used) ? (ws_size - used) : 0;
  long long chl = (long long)(remain / ((size_t)2 * 3 * NHID * 2)); // h1+h2 = 24576 B/row
  int CH = (int)(chl > NB ? NB : chl);
  CH &= ~127;
  if (CH < 128) CH = 128;
  f16* h1 = (f16*)alloc((size_t)CH * 3 * NHID * 2);
  f16* h2 = (f16*)alloc((size_t)CH * 3 * NHID * 2);
  int nchunks = (NB + CH - 1) / CH;

  k_prepW<<<dim3(NIN / 32, NHID / 32), 256, 0, stream>>>(W1, W1T, NIN, NHID);
  k_prepW<<<dim3(NHID / 32, NHID / 32), 256, 0, stream>>>(W2, W2T, NHID, NHID);
  k_prepW<<<dim3(NHID / 32, NOUTP / 32), 256, 0, stream>>>(W3, W3T, NHID, NOUT);
  k_splitX<<<(NB * NH) / 256, 256, 0, stream>>>(x, xm3);
  k_init<<<(NB * NM) / 256, 256, 0, stream>>>(xm3, fpb, list0, cnt);

  for (int t = 0; t < ITERS; ++t) {
    const int* lc = (t & 1) ? list1 : list0;
    int* ln       = (t & 1) ? list0 : list1;
    const int* cc = cnt + t;
    int* cn       = cnt + t + 1;
    for (int c = 0; c < nchunks; ++c) {
      int off = c * CH;
      int rows = NB - off; if (rows > CH) rows = CH;
      int g1 = (CH / 64) * 16;
      k_l1<<<g1, 256, 0, stream>>>(xm3, W1T, b1, h1, lc, cc, off, rows);
      k_l2<<<g1, 256, 0, stream>>>(h1, W2T, b2, h2, cc, off, rows);
      int g3 = (CH / 64) * 6;
      k_l3<<<g3, 256, 0, stream>>>(h2, W3T, b3, xm3, probs, hvb, lc, cc, off, rows);
    }
    k_update<<<NB / 256, 256, 0, stream>>>(lc, ln, hvb, probs, fpb, cc, cn);
  }
  k_final<<<NB / 256, 256, 0, stream>>>(fpb, out);
}

// Round 9
// 4392.473 us; speedup vs baseline: 2.0169x; 1.6921x over previous
//
#include <hip/hip_runtime.h>
#include <math.h>

typedef _Float16 f16;
typedef _Float16 f16x8 __attribute__((ext_vector_type(8)));
typedef float f32x4 __attribute__((ext_vector_type(4)));

#define NB 32768
#define NH 512
#define NM 128
#define NIN 640
#define NHID 2048
#define NOUT 642
#define NOUTP 768
#define ITERS 16
// 2-split f16: v = a0 + a1*EPS1,  EPS1=2^-11  (error ~3*2^-22 per product)
#define S1 2048.0f
#define EPS1 4.8828125e-4f

__device__ __forceinline__ void gload16(const void* g, void* lds) {
  __builtin_amdgcn_global_load_lds(
      reinterpret_cast<const __attribute__((address_space(1))) unsigned int*>((uintptr_t)g),
      reinterpret_cast<__attribute__((address_space(3))) unsigned int*>((unsigned int)(uintptr_t)lds),
      16, 0, 0);
}

__device__ __forceinline__ f32x4 mfma16(f16x8 a, f16x8 b, f32x4 c) {
  return __builtin_amdgcn_mfma_f32_16x16x32_f16(a, b, c, 0, 0, 0);
}

__device__ __forceinline__ void split2(float v, f16& a0, f16& a1) {
  a0 = (f16)v;
  a1 = (f16)((v - (float)a0) * S1);
}

// ---------------- weight transpose + 2-split: W[K][Nreal] -> WT[n][2][K] ----------------
__global__ void k_prepW(const float* __restrict__ W, f16* __restrict__ WT,
                        int K, int Nreal) {
  __shared__ float tile[32][33];
  int k0 = blockIdx.x * 32, n0 = blockIdx.y * 32;
  int tx = threadIdx.x & 31, ty = threadIdx.x >> 5;
#pragma unroll
  for (int r = 0; r < 4; ++r) {
    int kk = ty + 8 * r;
    int n = n0 + tx;
    tile[kk][tx] = (n < Nreal) ? W[(size_t)(k0 + kk) * Nreal + n] : 0.0f;
  }
  __syncthreads();
#pragma unroll
  for (int r = 0; r < 4; ++r) {
    int nl = ty + 8 * r;
    float v = tile[tx][nl];
    f16 a0, a1; split2(v, a0, a1);
    size_t o = (size_t)(n0 + nl) * (2 * K) + k0 + tx;
    WT[o] = a0; WT[o + K] = a1;
  }
}

// ---------------- split x into merged state xm2[row][2][640] (x cols 0..511) ----------------
__global__ void k_splitX(const float* __restrict__ x, f16* __restrict__ xm2) {
  int i = blockIdx.x * 256 + threadIdx.x;
  int row = i >> 9, c = i & 511;
  f16 a0, a1; split2(x[i], a0, a1);
  size_t o = (size_t)row * (2 * NIN) + c;
  xm2[o] = a0; xm2[o + NIN] = a1;
}

// ---------------- init mem part of xm2 (cols 512..639), fp/list/cnt ----------------
__global__ void k_init(f16* __restrict__ xm2, float* __restrict__ fpb,
                       int* __restrict__ list0, int* __restrict__ cnt) {
  int gid = blockIdx.x * blockDim.x + threadIdx.x;
  if (gid < NB * NM) {
    int row = gid >> 7, c = gid & 127;
    size_t o = (size_t)row * (2 * NIN) + 512 + c;
    xm2[o] = (f16)((c == 0) ? 16.0f : 0.0f);
    xm2[o + NIN] = (f16)0.0f;
  }
  if (gid < NB) { fpb[gid] = 0.0f; list0[gid] = gid; }
  if (gid < 32) cnt[gid] = (gid == 0) ? NB : 0;
}

// ===== GEMM: 64x128 tile, BK=32, 256 thr = 4 waves, wave tile 64x32, 3-pass 2-split =====
// LDS per buffer: A planes 64x32 @ {0,2048}, B planes 128x32 @ {4096,8192} (f16 units).
// Buffer stride 12288 f16 (24 KB); double-buffered 48 KB -> 3 blocks/CU.
// k-slot XOR-swizzle via pre-swizzled global source (r7 counter: 0 bank conflicts).

#define GEMM_PREAMBLE()                                                     \
  int tid = threadIdx.x;                                                    \
  int w = tid >> 6, lane = tid & 63;                                        \
  int lm = lane & 15, kb = lane >> 4;                                       \
  int kidx = ((kb ^ ((lm >> 1) & 3)) << 3);                                 \
  int ksrc = (((tid & 3) ^ ((tid >> 3) & 3)) << 3);                         \
  int stg = tid * 8;                                                        \
  int afo[4], bfo[2];                                                       \
  _Pragma("unroll") for (int m = 0; m < 4; ++m)                             \
    afo[m] = (m * 16 + lm) * 32 + kidx;                                     \
  _Pragma("unroll") for (int n = 0; n < 2; ++n)                             \
    bfo[n] = (w * 32 + n * 16 + lm) * 32 + kidx + 4096;                     \
  f32x4 acc0[4][2], acc1[4][2];                                             \
  _Pragma("unroll") for (int m = 0; m < 4; ++m)                             \
  _Pragma("unroll") for (int n = 0; n < 2; ++n) {                           \
    acc0[m][n] = (f32x4)0.0f; acc1[m][n] = (f32x4)0.0f;                     \
  }

#define GEMM_COMPUTE(BASE)                                                  \
  {                                                                         \
    const f16* _sb = (BASE);                                                \
    f16x8 fa0[4], fa1[4], fb0[2], fb1[2];                                   \
    _Pragma("unroll") for (int m = 0; m < 4; ++m) {                         \
      fa0[m] = *(const f16x8*)&_sb[afo[m]];                                 \
      fa1[m] = *(const f16x8*)&_sb[2048 + afo[m]];                          \
    }                                                                       \
    _Pragma("unroll") for (int n = 0; n < 2; ++n) {                         \
      fb0[n] = *(const f16x8*)&_sb[bfo[n]];                                 \
      fb1[n] = *(const f16x8*)&_sb[4096 + bfo[n]];                          \
    }                                                                       \
    __builtin_amdgcn_s_setprio(1);                                          \
    _Pragma("unroll") for (int m = 0; m < 4; ++m)                           \
    _Pragma("unroll") for (int n = 0; n < 2; ++n) {                         \
      acc0[m][n] = mfma16(fa0[m], fb0[n], acc0[m][n]);                      \
      acc1[m][n] = mfma16(fa0[m], fb1[n], acc1[m][n]);                      \
      acc1[m][n] = mfma16(fa1[m], fb0[n], acc1[m][n]);                      \
    }                                                                       \
    __builtin_amdgcn_s_setprio(0);                                          \
  }

// stage one 32-k step: A 2 planes (1 sweep each) + B 2 planes (2 sweeps each) = 6 loads/thread
#define STAGE6(K0, DST, PSA, PSB)                                           \
  {                                                                         \
    _Pragma("unroll") for (int s = 0; s < 2; ++s)                           \
      gload16(pA + s * (PSA) + (K0), (DST) + s * 2048 + stg);               \
    _Pragma("unroll") for (int s = 0; s < 2; ++s) {                         \
      gload16(pB + s * (PSB) + (K0), (DST) + 4096 + s * 4096 + stg);        \
      gload16(pB2 + s * (PSB) + (K0), (DST) + 6144 + s * 4096 + stg);       \
    }                                                                       \
  }

#define GEMM_PIPELOOP(KTOT, PSA, PSB)                                       \
  STAGE6(0, &SB[0], PSA, PSB);                                              \
  __syncthreads();                                                          \
  {                                                                         \
    int pb = 0;                                                             \
    for (int k0 = 0; k0 < (KTOT); k0 += 32, pb ^= 1) {                      \
      if (k0 + 32 < (KTOT))                                                 \
        STAGE6(k0 + 32, pb ? &SB[0] : &SB[12288], PSA, PSB);                \
      GEMM_COMPUTE(pb ? &SB[12288] : &SB[0]);                               \
      __syncthreads();                                                      \
    }                                                                       \
  }

#define COMBINE(m, n, q) (acc0[m][n][q] + EPS1 * acc1[m][n][q])

// XCD-affine swizzle for 16 col-tiles: ny = (id&7) + 8*bit3 -> each XCD owns 2 weight panels
#define MAP16(ID, BX, NY) int NY = ((ID) & 7) + 8 * (((ID) >> 3) & 1); int BX = (ID) >> 4;

// ---------------- layer 1: gather xm2 @ W1T, relu+b1 -> h1 (2-split) ----------------
__global__ __launch_bounds__(256) void k_l1(
    const f16* __restrict__ xm2, const f16* __restrict__ WT,
    const float* __restrict__ b1, f16* __restrict__ h1,
    const int* __restrict__ list, const int* __restrict__ cntp,
    int chunk_off, int chunk_rows) {
  int cnt = *cntp;
  MAP16(blockIdx.x, bx, ny);
  int lm0 = bx * 64;
  if (chunk_off + lm0 >= cnt) return;
  int lim = cnt - chunk_off; if (lim > chunk_rows) lim = chunk_rows;
  int n0 = ny * 128;

  __shared__ f16 SB[2 * 12288];
  GEMM_PREAMBLE();

  int pu = chunk_off + lm0 + (tid >> 2);
  int idx = list[pu < cnt ? pu : (cnt - 1)];
  const f16* pA = xm2 + (size_t)idx * (2 * NIN) + ksrc;
  const f16* pB = WT + (size_t)(n0 + (tid >> 2)) * (2 * NIN) + ksrc;
  const f16* pB2 = pB + (size_t)64 * (2 * NIN);

  GEMM_PIPELOOP(NIN, NIN, NIN);

#pragma unroll
  for (int n = 0; n < 2; ++n) {
    int col = n0 + w * 32 + n * 16 + lm;
    float bb = b1[col];
#pragma unroll
    for (int m = 0; m < 4; ++m) {
#pragma unroll
      for (int q = 0; q < 4; ++q) {
        int gr = lm0 + m * 16 + kb * 4 + q;
        if (gr < lim) {
          float v = fmaxf(COMBINE(m, n, q) + bb, 0.0f);
          f16 a0, a1; split2(v, a0, a1);
          size_t o = (size_t)gr * (2 * NHID) + col;
          h1[o] = a0; h1[o + NHID] = a1;
        }
      }
    }
  }
}

// ---------------- layer 2: h1 @ W2T, relu+b2 -> h2 (2-split) ----------------
__global__ __launch_bounds__(256) void k_l2(
    const f16* __restrict__ h1, const f16* __restrict__ WT,
    const float* __restrict__ b2, f16* __restrict__ h2,
    const int* __restrict__ cntp, int chunk_off, int chunk_rows) {
  int cnt = *cntp;
  MAP16(blockIdx.x, bx, ny);
  int lm0 = bx * 64;
  if (chunk_off + lm0 >= cnt) return;
  int lim = cnt - chunk_off; if (lim > chunk_rows) lim = chunk_rows;
  int n0 = ny * 128;

  __shared__ f16 SB[2 * 12288];
  GEMM_PREAMBLE();

  const f16* pA = h1 + (size_t)(lm0 + (tid >> 2)) * (2 * NHID) + ksrc;
  const f16* pB = WT + (size_t)(n0 + (tid >> 2)) * (2 * NHID) + ksrc;
  const f16* pB2 = pB + (size_t)64 * (2 * NHID);

  GEMM_PIPELOOP(NHID, NHID, NHID);

#pragma unroll
  for (int n = 0; n < 2; ++n) {
    int col = n0 + w * 32 + n * 16 + lm;
    float bb = b2[col];
#pragma unroll
    for (int m = 0; m < 4; ++m) {
#pragma unroll
      for (int q = 0; q < 4; ++q) {
        int gr = lm0 + m * 16 + kb * 4 + q;
        if (gr < lim) {
          float v = fmaxf(COMBINE(m, n, q) + bb, 0.0f);
          f16 a0, a1; split2(v, a0, a1);
          size_t o = (size_t)gr * (2 * NHID) + col;
          h2[o] = a0; h2[o + NHID] = a1;
        }
      }
    }
  }
}

// ---------------- layer 3: h2 @ W3T + b3 -> scatter probs/hv/xm2 ----------------
__global__ __launch_bounds__(256) void k_l3(
    const f16* __restrict__ h2, const f16* __restrict__ WT,
    const float* __restrict__ b3, f16* __restrict__ xm2,
    float* __restrict__ probs, float* __restrict__ hv,
    const int* __restrict__ list, const int* __restrict__ cntp,
    int chunk_off, int chunk_rows) {
  int cnt = *cntp;
  int id = blockIdx.x;
  int bx = id / 6, ny = id - bx * 6;
  int lm0 = bx * 64;
  if (chunk_off + lm0 >= cnt) return;
  int lim = cnt - chunk_off; if (lim > chunk_rows) lim = chunk_rows;
  int n0 = ny * 128;

  __shared__ f16 SB[2 * 12288];
  GEMM_PREAMBLE();

  const f16* pA = h2 + (size_t)(lm0 + (tid >> 2)) * (2 * NHID) + ksrc;
  const f16* pB = WT + (size_t)(n0 + (tid >> 2)) * (2 * NHID) + ksrc;
  const f16* pB2 = pB + (size_t)64 * (2 * NHID);

  GEMM_PIPELOOP(NHID, NHID, NHID);

  float bb[2]; int colv[2];
#pragma unroll
  for (int n = 0; n < 2; ++n) {
    colv[n] = n0 + w * 32 + n * 16 + lm;
    bb[n] = (colv[n] < NOUT) ? b3[colv[n]] : 0.0f;
  }
#pragma unroll
  for (int m = 0; m < 4; ++m) {
#pragma unroll
    for (int q = 0; q < 4; ++q) {
      int gr = lm0 + m * 16 + kb * 4 + q;
      if (gr >= lim) continue;
      int r = list[chunk_off + gr];
#pragma unroll
      for (int n = 0; n < 2; ++n) {
        int col = colv[n];
        if (col >= NOUT) continue;
        float v = COMBINE(m, n, q) + bb[n];
        if (col == 0) {
          probs[r] = v;
        } else if (col == 1) {
          hv[r] = v;
        } else if (col < 2 + NH) {
          f16 a0, a1; split2(v, a0, a1);
          size_t o = (size_t)r * (2 * NIN) + (col - 2);
          xm2[o] = a0; xm2[o + NIN] = a1;
        } else {
          f16 a0, a1; split2(v, a0, a1);
          size_t o = (size_t)r * (2 * NIN) + 512 + (col - 2 - NH);
          xm2[o] = a0; xm2[o + NIN] = a1;
        }
      }
    }
  }
}

// ---------------- halt update + compaction ----------------
__global__ void k_update(const int* __restrict__ listc, int* __restrict__ listn,
                         const float* __restrict__ hv, const float* __restrict__ probs,
                         float* __restrict__ fpb, const int* __restrict__ cntc,
                         int* __restrict__ cntn) {
  int i = blockIdx.x * blockDim.x + threadIdx.x;
  if (i >= *cntc) return;
  int r = listc[i];
  if (hv[r] > 0.0f) {
    fpb[r] = probs[r];
  } else {
    int pos = atomicAdd(cntn, 1);
    listn[pos] = r;
  }
}

// ---------------- final ----------------
__global__ void k_final(const float* __restrict__ fpb, float* __restrict__ out) {
  int i = blockIdx.x * blockDim.x + threadIdx.x;
  if (i < NB) {
    out[i] = 1.0f / (1.0f + expf(-fpb[i]));
    out[NB + i] = 0.0f;
  }
}

extern "C" void kernel_launch(void* const* d_in, const int* in_sizes, int n_in,
                              void* d_out, int out_size, void* d_ws, size_t ws_size,
                              hipStream_t stream) {
  const float* x  = (const float*)d_in[0];
  const float* W1 = (const float*)d_in[1];
  const float* b1 = (const float*)d_in[2];
  const float* W2 = (const float*)d_in[3];
  const float* b2 = (const float*)d_in[4];
  const float* W3 = (const float*)d_in[5];
  const float* b3 = (const float*)d_in[6];
  float* out = (float*)d_out;

  char* p = (char*)d_ws;
  auto alloc = [&](size_t bytes) {
    char* r = p;
    p += (bytes + 255) & ~(size_t)255;
    return r;
  };
  f16* xm2  = (f16*)alloc((size_t)NB * 2 * NIN * 2);     // 80 MiB
  f16* W1T  = (f16*)alloc((size_t)NHID * 2 * NIN * 2);   // 5 MiB
  f16* W2T  = (f16*)alloc((size_t)NHID * 2 * NHID * 2);  // 16 MiB
  f16* W3T  = (f16*)alloc((size_t)NOUTP * 2 * NHID * 2); // 6 MiB
  float* probs = (float*)alloc((size_t)NB * 4);
  float* hvb   = (float*)alloc((size_t)NB * 4);
  float* fpb   = (float*)alloc((size_t)NB * 4);
  int* list0   = (int*)alloc((size_t)NB * 4);
  int* list1   = (int*)alloc((size_t)NB * 4);
  int* cnt     = (int*)alloc(32 * 4);

  size_t used = (size_t)(p - (char*)d_ws);
  size_t remain = (ws_size > used) ? (ws_size - used) : 0;
  long long chl = (long long)(remain / ((size_t)2 * 2 * NHID * 2)); // h1+h2 = 16384 B/row
  int CH = (int)(chl > NB ? NB : chl);
  CH &= ~127;
  if (CH < 128) CH = 128;
  f16* h1 = (f16*)alloc((size_t)CH * 2 * NHID * 2);
  f16* h2 = (f16*)alloc((size_t)CH * 2 * NHID * 2);
  int nchunks = (NB + CH - 1) / CH;

  k_prepW<<<dim3(NIN / 32, NHID / 32), 256, 0, stream>>>(W1, W1T, NIN, NHID);
  k_prepW<<<dim3(NHID / 32, NHID / 32), 256, 0, stream>>>(W2, W2T, NHID, NHID);
  k_prepW<<<dim3(NHID / 32, NOUTP / 32), 256, 0, stream>>>(W3, W3T, NHID, NOUT);
  k_splitX<<<(NB * NH) / 256, 256, 0, stream>>>(x, xm2);
  k_init<<<(NB * NM) / 256, 256, 0, stream>>>(xm2, fpb, list0, cnt);

  for (int t = 0; t < ITERS; ++t) {
    const int* lc = (t & 1) ? list1 : list0;
    int* ln       = (t & 1) ? list0 : list1;
    const int* cc = cnt + t;
    int* cn       = cnt + t + 1;
    for (int c = 0; c < nchunks; ++c) {
      int off = c * CH;
      int rows = NB - off; if (rows > CH) rows = CH;
      int g1 = (CH / 64) * 16;
      k_l1<<<g1, 256, 0, stream>>>(xm2, W1T, b1, h1, lc, cc, off, rows);
      k_l2<<<g1, 256, 0, stream>>>(h1, W2T, b2, h2, cc, off, rows);
      int g3 = (CH / 64) * 6;
      k_l3<<<g3, 256, 0, stream>>>(h2, W3T, b3, xm2, probs, hvb, lc, cc, off, rows);
    }
    k_update<<<NB / 256, 256, 0, stream>>>(lc, ln, hvb, probs, fpb, cc, cn);
  }
  k_final<<<NB / 256, 256, 0, stream>>>(fpb, out);
}

// Round 10
// 3993.129 us; speedup vs baseline: 2.2186x; 1.1000x over previous
//
#include <hip/hip_runtime.h>
#include <math.h>

typedef _Float16 f16;
typedef _Float16 f16x8 __attribute__((ext_vector_type(8)));
typedef float f32x4 __attribute__((ext_vector_type(4)));

#define NB 32768
#define NH 512
#define NM 128
#define NIN 640
#define NHID 2048
#define NOUT 642
#define NOUTP 768
#define ITERS 16
// 2-split f16: v = a0 + a1*EPS1,  EPS1=2^-11
#define S1 2048.0f
#define EPS1 4.8828125e-4f

__device__ __forceinline__ void gload16(const void* g, void* lds) {
  __builtin_amdgcn_global_load_lds(
      reinterpret_cast<const __attribute__((address_space(1))) unsigned int*>((uintptr_t)g),
      reinterpret_cast<__attribute__((address_space(3))) unsigned int*>((unsigned int)(uintptr_t)lds),
      16, 0, 0);
}

__device__ __forceinline__ f32x4 mfma16(f16x8 a, f16x8 b, f32x4 c) {
  return __builtin_amdgcn_mfma_f32_16x16x32_f16(a, b, c, 0, 0, 0);
}

__device__ __forceinline__ void split2(float v, f16& a0, f16& a1) {
  a0 = (f16)v;
  a1 = (f16)((v - (float)a0) * S1);
}

// ---------------- weight transpose + 2-split: W[K][Nreal] -> WT[n][2][K] ----------------
__global__ void k_prepW(const float* __restrict__ W, f16* __restrict__ WT,
                        int K, int Nreal) {
  __shared__ float tile[32][33];
  int k0 = blockIdx.x * 32, n0 = blockIdx.y * 32;
  int tx = threadIdx.x & 31, ty = threadIdx.x >> 5;
#pragma unroll
  for (int r = 0; r < 4; ++r) {
    int kk = ty + 8 * r;
    int n = n0 + tx;
    tile[kk][tx] = (n < Nreal) ? W[(size_t)(k0 + kk) * Nreal + n] : 0.0f;
  }
  __syncthreads();
#pragma unroll
  for (int r = 0; r < 4; ++r) {
    int nl = ty + 8 * r;
    float v = tile[tx][nl];
    f16 a0, a1; split2(v, a0, a1);
    size_t o = (size_t)(n0 + nl) * (2 * K) + k0 + tx;
    WT[o] = a0; WT[o + K] = a1;
  }
}

// ---------------- split x into merged state xm2[row][2][640] (x cols 0..511) ----------------
__global__ void k_splitX(const float* __restrict__ x, f16* __restrict__ xm2) {
  int i = blockIdx.x * 256 + threadIdx.x;
  int row = i >> 9, c = i & 511;
  f16 a0, a1; split2(x[i], a0, a1);
  size_t o = (size_t)row * (2 * NIN) + c;
  xm2[o] = a0; xm2[o + NIN] = a1;
}

// ---------------- init mem part of xm2 (cols 512..639), fp/list/cnt ----------------
__global__ void k_init(f16* __restrict__ xm2, float* __restrict__ fpb,
                       int* __restrict__ list0, int* __restrict__ cnt) {
  int gid = blockIdx.x * blockDim.x + threadIdx.x;
  if (gid < NB * NM) {
    int row = gid >> 7, c = gid & 127;
    size_t o = (size_t)row * (2 * NIN) + 512 + c;
    xm2[o] = (f16)((c == 0) ? 16.0f : 0.0f);
    xm2[o + NIN] = (f16)0.0f;
  }
  if (gid < NB) { fpb[gid] = 0.0f; list0[gid] = gid; }
  if (gid < 32) cnt[gid] = (gid == 0) ? NB : 0;
}

// ===== GEMM: 128x128 tile, BK=32, 256 thr = 4 waves (2x2), wave tile 64x64, 3-pass 2-split =====
// LDS per buffer: A planes 128x32 @ {0,4096}, B planes 128x32 @ {8192,12288} (f16 units).
// Buffer stride 16384 f16 (32 KB); double-buffered 64 KB -> 2 blocks/CU.
// Ratio per wave K-step: 48 MFMA (~233cyc) vs 16 ds_read_b128 (~192cyc) -> MFMA-bound.
// k-slot XOR-swizzle via pre-swizzled global source (r7/r9 counters: 0 bank conflicts).

#define GEMM_PREAMBLE()                                                     \
  int tid = threadIdx.x;                                                    \
  int w = tid >> 6, lane = tid & 63;                                        \
  int wr = w >> 1, wc = w & 1;                                              \
  int lm = lane & 15, kb = lane >> 4;                                       \
  int kidx = ((kb ^ ((lm >> 1) & 3)) << 3);                                 \
  int ksrc = (((tid & 3) ^ ((tid >> 3) & 3)) << 3);                         \
  int stg = tid * 8;                                                        \
  int afo[4], bfo[4];                                                       \
  _Pragma("unroll") for (int m = 0; m < 4; ++m)                             \
    afo[m] = (wr * 64 + m * 16 + lm) * 32 + kidx;                           \
  _Pragma("unroll") for (int n = 0; n < 4; ++n)                             \
    bfo[n] = (wc * 64 + n * 16 + lm) * 32 + kidx + 8192;                    \
  f32x4 acc0[4][4], acc1[4][4];                                             \
  _Pragma("unroll") for (int m = 0; m < 4; ++m)                             \
  _Pragma("unroll") for (int n = 0; n < 4; ++n) {                           \
    acc0[m][n] = (f32x4)0.0f; acc1[m][n] = (f32x4)0.0f;                     \
  }

#define GEMM_COMPUTE(BASE)                                                  \
  {                                                                         \
    const f16* _sb = (BASE);                                                \
    f16x8 fa0[4], fa1[4], fb0[4], fb1[4];                                   \
    _Pragma("unroll") for (int m = 0; m < 4; ++m) {                         \
      fa0[m] = *(const f16x8*)&_sb[afo[m]];                                 \
      fa1[m] = *(const f16x8*)&_sb[4096 + afo[m]];                          \
    }                                                                       \
    _Pragma("unroll") for (int n = 0; n < 4; ++n) {                         \
      fb0[n] = *(const f16x8*)&_sb[bfo[n]];                                 \
      fb1[n] = *(const f16x8*)&_sb[4096 + bfo[n]];                          \
    }                                                                       \
    __builtin_amdgcn_s_setprio(1);                                          \
    _Pragma("unroll") for (int m = 0; m < 4; ++m)                           \
    _Pragma("unroll") for (int n = 0; n < 4; ++n) {                         \
      acc0[m][n] = mfma16(fa0[m], fb0[n], acc0[m][n]);                      \
      acc1[m][n] = mfma16(fa0[m], fb1[n], acc1[m][n]);                      \
      acc1[m][n] = mfma16(fa1[m], fb0[n], acc1[m][n]);                      \
    }                                                                       \
    __builtin_amdgcn_s_setprio(0);                                          \
  }

// stage one 32-k step: A 2 planes x 2 row-sweeps + B 2 planes x 2 row-sweeps = 8 loads/thread
#define STAGE8(K0, DST, PSA, PSB)                                           \
  {                                                                         \
    _Pragma("unroll") for (int s = 0; s < 2; ++s) {                         \
      gload16(pA + s * (PSA) + (K0), (DST) + s * 4096 + stg);               \
      gload16(pA2 + s * (PSA) + (K0), (DST) + 2048 + s * 4096 + stg);       \
    }                                                                       \
    _Pragma("unroll") for (int s = 0; s < 2; ++s) {                         \
      gload16(pB + s * (PSB) + (K0), (DST) + 8192 + s * 4096 + stg);        \
      gload16(pB2 + s * (PSB) + (K0), (DST) + 10240 + s * 4096 + stg);      \
    }                                                                       \
  }

#define GEMM_PIPELOOP(KTOT, PSA, PSB)                                       \
  STAGE8(0, &SB[0], PSA, PSB);                                              \
  __syncthreads();                                                          \
  {                                                                         \
    int pb = 0;                                                             \
    for (int k0 = 0; k0 < (KTOT); k0 += 32, pb ^= 1) {                      \
      if (k0 + 32 < (KTOT))                                                 \
        STAGE8(k0 + 32, pb ? &SB[0] : &SB[16384], PSA, PSB);                \
      GEMM_COMPUTE(pb ? &SB[16384] : &SB[0]);                               \
      __syncthreads();                                                      \
    }                                                                       \
  }

#define COMBINE(m, n, q) (acc0[m][n][q] + EPS1 * acc1[m][n][q])

// XCD-affine swizzle for 16 col-tiles: ny = (id&7) + 8*bit3 -> each XCD owns 2 weight panels
#define MAP16(ID, BX, NY) int NY = ((ID) & 7) + 8 * (((ID) >> 3) & 1); int BX = (ID) >> 4;

// ---------------- layer 1: gather xm2 @ W1T, relu+b1 -> h1 (2-split) ----------------
__global__ __launch_bounds__(256, 2) void k_l1(
    const f16* __restrict__ xm2, const f16* __restrict__ WT,
    const float* __restrict__ b1, f16* __restrict__ h1,
    const int* __restrict__ list, const int* __restrict__ cntp,
    int chunk_off, int chunk_rows) {
  int cnt = *cntp;
  MAP16(blockIdx.x, bx, ny);
  int lm0 = bx * 128;
  if (chunk_off + lm0 >= cnt) return;
  int lim = cnt - chunk_off; if (lim > chunk_rows) lim = chunk_rows;
  int n0 = ny * 128;

  __shared__ f16 SB[2 * 16384];
  GEMM_PREAMBLE();

  int pu = chunk_off + lm0 + (tid >> 2);
  int pu2 = pu + 64;
  int idx = list[pu < cnt ? pu : (cnt - 1)];
  int idx2 = list[pu2 < cnt ? pu2 : (cnt - 1)];
  const f16* pA = xm2 + (size_t)idx * (2 * NIN) + ksrc;
  const f16* pA2 = xm2 + (size_t)idx2 * (2 * NIN) + ksrc;
  const f16* pB = WT + (size_t)(n0 + (tid >> 2)) * (2 * NIN) + ksrc;
  const f16* pB2 = pB + (size_t)64 * (2 * NIN);

  GEMM_PIPELOOP(NIN, NIN, NIN);

#pragma unroll
  for (int n = 0; n < 4; ++n) {
    int col = n0 + wc * 64 + n * 16 + lm;
    float bb = b1[col];
#pragma unroll
    for (int m = 0; m < 4; ++m) {
#pragma unroll
      for (int q = 0; q < 4; ++q) {
        int gr = lm0 + wr * 64 + m * 16 + kb * 4 + q;
        if (gr < lim) {
          float v = fmaxf(COMBINE(m, n, q) + bb, 0.0f);
          f16 a0, a1; split2(v, a0, a1);
          size_t o = (size_t)gr * (2 * NHID) + col;
          h1[o] = a0; h1[o + NHID] = a1;
        }
      }
    }
  }
}

// ---------------- layer 2: h1 @ W2T, relu+b2 -> h2 (2-split) ----------------
__global__ __launch_bounds__(256, 2) void k_l2(
    const f16* __restrict__ h1, const f16* __restrict__ WT,
    const float* __restrict__ b2, f16* __restrict__ h2,
    const int* __restrict__ cntp, int chunk_off, int chunk_rows) {
  int cnt = *cntp;
  MAP16(blockIdx.x, bx, ny);
  int lm0 = bx * 128;
  if (chunk_off + lm0 >= cnt) return;
  int lim = cnt - chunk_off; if (lim > chunk_rows) lim = chunk_rows;
  int n0 = ny * 128;

  __shared__ f16 SB[2 * 16384];
  GEMM_PREAMBLE();

  const f16* pA = h1 + (size_t)(lm0 + (tid >> 2)) * (2 * NHID) + ksrc;
  const f16* pA2 = pA + (size_t)64 * (2 * NHID);
  const f16* pB = WT + (size_t)(n0 + (tid >> 2)) * (2 * NHID) + ksrc;
  const f16* pB2 = pB + (size_t)64 * (2 * NHID);

  GEMM_PIPELOOP(NHID, NHID, NHID);

#pragma unroll
  for (int n = 0; n < 4; ++n) {
    int col = n0 + wc * 64 + n * 16 + lm;
    float bb = b2[col];
#pragma unroll
    for (int m = 0; m < 4; ++m) {
#pragma unroll
      for (int q = 0; q < 4; ++q) {
        int gr = lm0 + wr * 64 + m * 16 + kb * 4 + q;
        if (gr < lim) {
          float v = fmaxf(COMBINE(m, n, q) + bb, 0.0f);
          f16 a0, a1; split2(v, a0, a1);
          size_t o = (size_t)gr * (2 * NHID) + col;
          h2[o] = a0; h2[o + NHID] = a1;
        }
      }
    }
  }
}

// ---------------- layer 3: h2 @ W3T + b3 -> scatter probs/hv/xm2 ----------------
__global__ __launch_bounds__(256, 2) void k_l3(
    const f16* __restrict__ h2, const f16* __restrict__ WT,
    const float* __restrict__ b3, f16* __restrict__ xm2,
    float* __restrict__ probs, float* __restrict__ hv,
    const int* __restrict__ list, const int* __restrict__ cntp,
    int chunk_off, int chunk_rows) {
  int cnt = *cntp;
  int id = blockIdx.x;
  int bx = id / 6, ny = id - bx * 6;
  int lm0 = bx * 128;
  if (chunk_off + lm0 >= cnt) return;
  int lim = cnt - chunk_off; if (lim > chunk_rows) lim = chunk_rows;
  int n0 = ny * 128;

  __shared__ f16 SB[2 * 16384];
  GEMM_PREAMBLE();

  const f16* pA = h2 + (size_t)(lm0 + (tid >> 2)) * (2 * NHID) + ksrc;
  const f16* pA2 = pA + (size_t)64 * (2 * NHID);
  const f16* pB = WT + (size_t)(n0 + (tid >> 2)) * (2 * NHID) + ksrc;
  const f16* pB2 = pB + (size_t)64 * (2 * NHID);

  GEMM_PIPELOOP(NHID, NHID, NHID);

  float bb[4]; int colv[4];
#pragma unroll
  for (int n = 0; n < 4; ++n) {
    colv[n] = n0 + wc * 64 + n * 16 + lm;
    bb[n] = (colv[n] < NOUT) ? b3[colv[n]] : 0.0f;
  }
#pragma unroll
  for (int m = 0; m < 4; ++m) {
#pragma unroll
    for (int q = 0; q < 4; ++q) {
      int gr = lm0 + wr * 64 + m * 16 + kb * 4 + q;
      if (gr >= lim) continue;
      int r = list[chunk_off + gr];
#pragma unroll
      for (int n = 0; n < 4; ++n) {
        int col = colv[n];
        if (col >= NOUT) continue;
        float v = COMBINE(m, n, q) + bb[n];
        if (col == 0) {
          probs[r] = v;
        } else if (col == 1) {
          hv[r] = v;
        } else if (col < 2 + NH) {
          f16 a0, a1; split2(v, a0, a1);
          size_t o = (size_t)r * (2 * NIN) + (col - 2);
          xm2[o] = a0; xm2[o + NIN] = a1;
        } else {
          f16 a0, a1; split2(v, a0, a1);
          size_t o = (size_t)r * (2 * NIN) + 512 + (col - 2 - NH);
          xm2[o] = a0; xm2[o + NIN] = a1;
        }
      }
    }
  }
}

// ---------------- halt update + compaction ----------------
__global__ void k_update(const int* __restrict__ listc, int* __restrict__ listn,
                         const float* __restrict__ hv, const float* __restrict__ probs,
                         float* __restrict__ fpb, const int* __restrict__ cntc,
                         int* __restrict__ cntn) {
  int i = blockIdx.x * blockDim.x + threadIdx.x;
  if (i >= *cntc) return;
  int r = listc[i];
  if (hv[r] > 0.0f) {
    fpb[r] = probs[r];
  } else {
    int pos = atomicAdd(cntn, 1);
    listn[pos] = r;
  }
}

// ---------------- final ----------------
__global__ void k_final(const float* __restrict__ fpb, float* __restrict__ out) {
  int i = blockIdx.x * blockDim.x + threadIdx.x;
  if (i < NB) {
    out[i] = 1.0f / (1.0f + expf(-fpb[i]));
    out[NB + i] = 0.0f;
  }
}

extern "C" void kernel_launch(void* const* d_in, const int* in_sizes, int n_in,
                              void* d_out, int out_size, void* d_ws, size_t ws_size,
                              hipStream_t stream) {
  const float* x  = (const float*)d_in[0];
  const float* W1 = (const float*)d_in[1];
  const float* b1 = (const float*)d_in[2];
  const float* W2 = (const float*)d_in[3];
  const float* b2 = (const float*)d_in[4];
  const float* W3 = (const float*)d_in[5];
  const float* b3 = (const float*)d_in[6];
  float* out = (float*)d_out;

  char* p = (char*)d_ws;
  auto alloc = [&](size_t bytes) {
    char* r = p;
    p += (bytes + 255) & ~(size_t)255;
    return r;
  };
  f16* xm2  = (f16*)alloc((size_t)NB * 2 * NIN * 2);     // 80 MiB
  f16* W1T  = (f16*)alloc((size_t)NHID * 2 * NIN * 2);   // 5 MiB
  f16* W2T  = (f16*)alloc((size_t)NHID * 2 * NHID * 2);  // 16 MiB
  f16* W3T  = (f16*)alloc((size_t)NOUTP * 2 * NHID * 2); // 6 MiB
  float* probs = (float*)alloc((size_t)NB * 4);
  float* hvb   = (float*)alloc((size_t)NB * 4);
  float* fpb   = (float*)alloc((size_t)NB * 4);
  int* list0   = (int*)alloc((size_t)NB * 4);
  int* list1   = (int*)alloc((size_t)NB * 4);
  int* cnt     = (int*)alloc(32 * 4);

  size_t used = (size_t)(p - (char*)d_ws);
  size_t remain = (ws_size > used) ? (ws_size - used) : 0;
  long long chl = (long long)(remain / ((size_t)2 * 2 * NHID * 2)); // h1+h2 = 16384 B/row
  int CH = (int)(chl > NB ? NB : chl);
  CH &= ~127;
  if (CH < 128) CH = 128;
  f16* h1 = (f16*)alloc((size_t)CH * 2 * NHID * 2);
  f16* h2 = (f16*)alloc((size_t)CH * 2 * NHID * 2);
  int nchunks = (NB + CH - 1) / CH;

  k_prepW<<<dim3(NIN / 32, NHID / 32), 256, 0, stream>>>(W1, W1T, NIN, NHID);
  k_prepW<<<dim3(NHID / 32, NHID / 32), 256, 0, stream>>>(W2, W2T, NHID, NHID);
  k_prepW<<<dim3(NHID / 32, NOUTP / 32), 256, 0, stream>>>(W3, W3T, NHID, NOUT);
  k_splitX<<<(NB * NH) / 256, 256, 0, stream>>>(x, xm2);
  k_init<<<(NB * NM) / 256, 256, 0, stream>>>(xm2, fpb, list0, cnt);

  for (int t = 0; t < ITERS; ++t) {
    const int* lc = (t & 1) ? list1 : list0;
    int* ln       = (t & 1) ? list0 : list1;
    const int* cc = cnt + t;
    int* cn       = cnt + t + 1;
    for (int c = 0; c < nchunks; ++c) {
      int off = c * CH;
      int rows = NB - off; if (rows > CH) rows = CH;
      int g1 = (CH / 128) * 16;
      k_l1<<<g1, 256, 0, stream>>>(xm2, W1T, b1, h1, lc, cc, off, rows);
      k_l2<<<g1, 256, 0, stream>>>(h1, W2T, b2, h2, cc, off, rows);
      int g3 = (CH / 128) * 6;
      k_l3<<<g3, 256, 0, stream>>>(h2, W3T, b3, xm2, probs, hvb, lc, cc, off, rows);
    }
    k_update<<<NB / 256, 256, 0, stream>>>(lc, ln, hvb, probs, fpb, cc, cn);
  }
  k_final<<<NB / 256, 256, 0, stream>>>(fpb, out);
}

// Round 11
// 3881.191 us; speedup vs baseline: 2.2826x; 1.0288x over previous
//
#include <hip/hip_runtime.h>
#include <math.h>

typedef _Float16 f16;
typedef _Float16 f16x8 __attribute__((ext_vector_type(8)));
typedef float f32x4 __attribute__((ext_vector_type(4)));

#define NB 32768
#define NH 512
#define NM 128
#define NIN 640
#define NHID 2048
#define NOUT 642
#define NOUTP 768
#define ITERS 16
// 2-split f16: v = a0 + a1*EPS1,  EPS1=2^-11
#define S1 2048.0f
#define EPS1 4.8828125e-4f

__device__ __forceinline__ void gload16(const void* g, void* lds) {
  __builtin_amdgcn_global_load_lds(
      reinterpret_cast<const __attribute__((address_space(1))) unsigned int*>((uintptr_t)g),
      reinterpret_cast<__attribute__((address_space(3))) unsigned int*>((unsigned int)(uintptr_t)lds),
      16, 0, 0);
}

__device__ __forceinline__ f32x4 mfma16(f16x8 a, f16x8 b, f32x4 c) {
  return __builtin_amdgcn_mfma_f32_16x16x32_f16(a, b, c, 0, 0, 0);
}

__device__ __forceinline__ void split2(float v, f16& a0, f16& a1) {
  a0 = (f16)v;
  a1 = (f16)((v - (float)a0) * S1);
}

// ---------------- weight transpose + 2-split: W[K][Nreal] -> WT[n][2][K] ----------------
__global__ void k_prepW(const float* __restrict__ W, f16* __restrict__ WT,
                        int K, int Nreal) {
  __shared__ float tile[32][33];
  int k0 = blockIdx.x * 32, n0 = blockIdx.y * 32;
  int tx = threadIdx.x & 31, ty = threadIdx.x >> 5;
#pragma unroll
  for (int r = 0; r < 4; ++r) {
    int kk = ty + 8 * r;
    int n = n0 + tx;
    tile[kk][tx] = (n < Nreal) ? W[(size_t)(k0 + kk) * Nreal + n] : 0.0f;
  }
  __syncthreads();
#pragma unroll
  for (int r = 0; r < 4; ++r) {
    int nl = ty + 8 * r;
    float v = tile[tx][nl];
    f16 a0, a1; split2(v, a0, a1);
    size_t o = (size_t)(n0 + nl) * (2 * K) + k0 + tx;
    WT[o] = a0; WT[o + K] = a1;
  }
}

// ---------------- split x into merged state xm2[row][2][640] (x cols 0..511) ----------------
__global__ void k_splitX(const float* __restrict__ x, f16* __restrict__ xm2) {
  int i = blockIdx.x * 256 + threadIdx.x;
  int row = i >> 9, c = i & 511;
  f16 a0, a1; split2(x[i], a0, a1);
  size_t o = (size_t)row * (2 * NIN) + c;
  xm2[o] = a0; xm2[o + NIN] = a1;
}

// ---------------- init mem part of xm2 (cols 512..639), fp/list/cnt ----------------
__global__ void k_init(f16* __restrict__ xm2, float* __restrict__ fpb,
                       int* __restrict__ list0, int* __restrict__ cnt) {
  int gid = blockIdx.x * blockDim.x + threadIdx.x;
  if (gid < NB * NM) {
    int row = gid >> 7, c = gid & 127;
    size_t o = (size_t)row * (2 * NIN) + 512 + c;
    xm2[o] = (f16)((c == 0) ? 16.0f : 0.0f);
    xm2[o + NIN] = (f16)0.0f;
  }
  if (gid < NB) { fpb[gid] = 0.0f; list0[gid] = gid; }
  if (gid < 32) cnt[gid] = (gid == 0) ? NB : 0;
}

// ===== GEMM: 128x128 tile, BK=32, 256 thr = 4 waves (2x2), wave tile 64x64, 3-pass 2-split =====
// LDS per buffer: A planes 128x32 @ {0,4096}, B planes 128x32 @ {8192,12288} (f16 units).
// Buffer stride 16384 f16 (32 KB); double-buffered 64 KB -> 2 blocks/CU.
// r10 measured: ~880 TF f16 in k_l2 (structure ceiling); 0 bank conflicts.

#define GEMM_PREAMBLE()                                                     \
  int tid = threadIdx.x;                                                    \
  int w = tid >> 6, lane = tid & 63;                                        \
  int wr = w >> 1, wc = w & 1;                                              \
  int lm = lane & 15, kb = lane >> 4;                                       \
  int kidx = ((kb ^ ((lm >> 1) & 3)) << 3);                                 \
  int ksrc = (((tid & 3) ^ ((tid >> 3) & 3)) << 3);                         \
  int stg = tid * 8;                                                        \
  int afo[4], bfo[4];                                                       \
  _Pragma("unroll") for (int m = 0; m < 4; ++m)                             \
    afo[m] = (wr * 64 + m * 16 + lm) * 32 + kidx;                           \
  _Pragma("unroll") for (int n = 0; n < 4; ++n)                             \
    bfo[n] = (wc * 64 + n * 16 + lm) * 32 + kidx + 8192;                    \
  f32x4 acc0[4][4], acc1[4][4];                                             \
  _Pragma("unroll") for (int m = 0; m < 4; ++m)                             \
  _Pragma("unroll") for (int n = 0; n < 4; ++n) {                           \
    acc0[m][n] = (f32x4)0.0f; acc1[m][n] = (f32x4)0.0f;                     \
  }

#define GEMM_COMPUTE(BASE)                                                  \
  {                                                                         \
    const f16* _sb = (BASE);                                                \
    f16x8 fa0[4], fa1[4], fb0[4], fb1[4];                                   \
    _Pragma("unroll") for (int m = 0; m < 4; ++m) {                         \
      fa0[m] = *(const f16x8*)&_sb[afo[m]];                                 \
      fa1[m] = *(const f16x8*)&_sb[4096 + afo[m]];                          \
    }                                                                       \
    _Pragma("unroll") for (int n = 0; n < 4; ++n) {                         \
      fb0[n] = *(const f16x8*)&_sb[bfo[n]];                                 \
      fb1[n] = *(const f16x8*)&_sb[4096 + bfo[n]];                          \
    }                                                                       \
    __builtin_amdgcn_s_setprio(1);                                          \
    _Pragma("unroll") for (int m = 0; m < 4; ++m)                           \
    _Pragma("unroll") for (int n = 0; n < 4; ++n) {                         \
      acc0[m][n] = mfma16(fa0[m], fb0[n], acc0[m][n]);                      \
      acc1[m][n] = mfma16(fa0[m], fb1[n], acc1[m][n]);                      \
      acc1[m][n] = mfma16(fa1[m], fb0[n], acc1[m][n]);                      \
    }                                                                       \
    __builtin_amdgcn_s_setprio(0);                                          \
  }

// stage one 32-k step: A 2 planes x 2 row-sweeps + B 2 planes x 2 row-sweeps = 8 loads/thread
#define STAGE8(K0, DST, PSA, PSB)                                           \
  {                                                                         \
    _Pragma("unroll") for (int s = 0; s < 2; ++s) {                         \
      gload16(pA + s * (PSA) + (K0), (DST) + s * 4096 + stg);               \
      gload16(pA2 + s * (PSA) + (K0), (DST) + 2048 + s * 4096 + stg);       \
    }                                                                       \
    _Pragma("unroll") for (int s = 0; s < 2; ++s) {                         \
      gload16(pB + s * (PSB) + (K0), (DST) + 8192 + s * 4096 + stg);        \
      gload16(pB2 + s * (PSB) + (K0), (DST) + 10240 + s * 4096 + stg);      \
    }                                                                       \
  }

#define GEMM_PIPELOOP(KTOT, PSA, PSB)                                       \
  STAGE8(0, &SB[0], PSA, PSB);                                              \
  __syncthreads();                                                          \
  {                                                                         \
    int pb = 0;                                                             \
    for (int k0 = 0; k0 < (KTOT); k0 += 32, pb ^= 1) {                      \
      if (k0 + 32 < (KTOT))                                                 \
        STAGE8(k0 + 32, pb ? &SB[0] : &SB[16384], PSA, PSB);                \
      GEMM_COMPUTE(pb ? &SB[16384] : &SB[0]);                               \
      __syncthreads();                                                      \
    }                                                                       \
  }

#define COMBINE(m, n, q) (acc0[m][n][q] + EPS1 * acc1[m][n][q])

// XCD-affine swizzle for 16 col-tiles: ny = (id&7) + 8*bit3 -> each XCD owns 2 weight panels
#define MAP16(ID, BX, NY) int NY = ((ID) & 7) + 8 * (((ID) >> 3) & 1); int BX = (ID) >> 4;

// ---------------- layer 1: gather xm2 @ W1T, relu+b1 -> h1 (2-split) ----------------
__global__ __launch_bounds__(256, 2) void k_l1(
    const f16* __restrict__ xm2, const f16* __restrict__ WT,
    const float* __restrict__ b1, f16* __restrict__ h1,
    const int* __restrict__ list, const int* __restrict__ cntp,
    int chunk_off, int chunk_rows) {
  int cnt = *cntp;
  MAP16(blockIdx.x, bx, ny);
  int lm0 = bx * 128;
  if (chunk_off + lm0 >= cnt) return;
  int lim = cnt - chunk_off; if (lim > chunk_rows) lim = chunk_rows;
  int n0 = ny * 128;

  __shared__ f16 SB[2 * 16384];
  GEMM_PREAMBLE();

  int pu = chunk_off + lm0 + (tid >> 2);
  int pu2 = pu + 64;
  int idx = list[pu < cnt ? pu : (cnt - 1)];
  int idx2 = list[pu2 < cnt ? pu2 : (cnt - 1)];
  const f16* pA = xm2 + (size_t)idx * (2 * NIN) + ksrc;
  const f16* pA2 = xm2 + (size_t)idx2 * (2 * NIN) + ksrc;
  const f16* pB = WT + (size_t)(n0 + (tid >> 2)) * (2 * NIN) + ksrc;
  const f16* pB2 = pB + (size_t)64 * (2 * NIN);

  GEMM_PIPELOOP(NIN, NIN, NIN);

#pragma unroll
  for (int n = 0; n < 4; ++n) {
    int col = n0 + wc * 64 + n * 16 + lm;
    float bb = b1[col];
#pragma unroll
    for (int m = 0; m < 4; ++m) {
#pragma unroll
      for (int q = 0; q < 4; ++q) {
        int gr = lm0 + wr * 64 + m * 16 + kb * 4 + q;
        if (gr < lim) {
          float v = fmaxf(COMBINE(m, n, q) + bb, 0.0f);
          f16 a0, a1; split2(v, a0, a1);
          size_t o = (size_t)gr * (2 * NHID) + col;
          h1[o] = a0; h1[o + NHID] = a1;
        }
      }
    }
  }
}

// ---------------- layer 2: h1 @ W2T, relu+b2 -> h2 (2-split) ----------------
__global__ __launch_bounds__(256, 2) void k_l2(
    const f16* __restrict__ h1, const f16* __restrict__ WT,
    const float* __restrict__ b2, f16* __restrict__ h2,
    const int* __restrict__ cntp, int chunk_off, int chunk_rows) {
  int cnt = *cntp;
  MAP16(blockIdx.x, bx, ny);
  int lm0 = bx * 128;
  if (chunk_off + lm0 >= cnt) return;
  int lim = cnt - chunk_off; if (lim > chunk_rows) lim = chunk_rows;
  int n0 = ny * 128;

  __shared__ f16 SB[2 * 16384];
  GEMM_PREAMBLE();

  const f16* pA = h1 + (size_t)(lm0 + (tid >> 2)) * (2 * NHID) + ksrc;
  const f16* pA2 = pA + (size_t)64 * (2 * NHID);
  const f16* pB = WT + (size_t)(n0 + (tid >> 2)) * (2 * NHID) + ksrc;
  const f16* pB2 = pB + (size_t)64 * (2 * NHID);

  GEMM_PIPELOOP(NHID, NHID, NHID);

#pragma unroll
  for (int n = 0; n < 4; ++n) {
    int col = n0 + wc * 64 + n * 16 + lm;
    float bb = b2[col];
#pragma unroll
    for (int m = 0; m < 4; ++m) {
#pragma unroll
      for (int q = 0; q < 4; ++q) {
        int gr = lm0 + wr * 64 + m * 16 + kb * 4 + q;
        if (gr < lim) {
          float v = fmaxf(COMBINE(m, n, q) + bb, 0.0f);
          f16 a0, a1; split2(v, a0, a1);
          size_t o = (size_t)gr * (2 * NHID) + col;
          h2[o] = a0; h2[o + NHID] = a1;
        }
      }
    }
  }
}

// ---------------- layer 3: h2 @ W3T + b3 -> scatter xm2; ny==0 blocks also do halt
// update + compaction inline (probs=col0 / hv=col1 stashed in LDS after the GEMM) ----------------
__global__ __launch_bounds__(256, 2) void k_l3(
    const f16* __restrict__ h2, const f16* __restrict__ WT,
    const float* __restrict__ b3, f16* __restrict__ xm2,
    float* __restrict__ fpb,
    const int* __restrict__ list, int* __restrict__ listn,
    const int* __restrict__ cntp, int* __restrict__ cntn,
    int chunk_off, int chunk_rows) {
  int cnt = *cntp;
  int id = blockIdx.x;
  int bx = id / 6, ny = id - bx * 6;
  int lm0 = bx * 128;
  if (chunk_off + lm0 >= cnt) return;
  int lim = cnt - chunk_off; if (lim > chunk_rows) lim = chunk_rows;
  int n0 = ny * 128;

  __shared__ f16 SB[2 * 16384];
  GEMM_PREAMBLE();

  const f16* pA = h2 + (size_t)(lm0 + (tid >> 2)) * (2 * NHID) + ksrc;
  const f16* pA2 = pA + (size_t)64 * (2 * NHID);
  const f16* pB = WT + (size_t)(n0 + (tid >> 2)) * (2 * NHID) + ksrc;
  const f16* pB2 = pB + (size_t)64 * (2 * NHID);

  GEMM_PIPELOOP(NHID, NHID, NHID);

  float* SBp = (float*)SB;          // probs[128]  (LDS reuse; GEMM reads done)
  float* SBh = (float*)SB + 128;    // hv[128]

  float bb[4]; int colv[4];
#pragma unroll
  for (int n = 0; n < 4; ++n) {
    colv[n] = n0 + wc * 64 + n * 16 + lm;
    bb[n] = (colv[n] < NOUT) ? b3[colv[n]] : 0.0f;
  }
#pragma unroll
  for (int m = 0; m < 4; ++m) {
#pragma unroll
    for (int q = 0; q < 4; ++q) {
      int gr = lm0 + wr * 64 + m * 16 + kb * 4 + q;
      if (gr >= lim) continue;
      int r = list[chunk_off + gr];
#pragma unroll
      for (int n = 0; n < 4; ++n) {
        int col = colv[n];
        if (col >= NOUT) continue;
        float v = COMBINE(m, n, q) + bb[n];
        if (col == 0) {
          SBp[gr - lm0] = v;
        } else if (col == 1) {
          SBh[gr - lm0] = v;
        } else if (col < 2 + NH) {
          f16 a0, a1; split2(v, a0, a1);
          size_t o = (size_t)r * (2 * NIN) + (col - 2);
          xm2[o] = a0; xm2[o + NIN] = a1;
        } else {
          f16 a0, a1; split2(v, a0, a1);
          size_t o = (size_t)r * (2 * NIN) + 512 + (col - 2 - NH);
          xm2[o] = a0; xm2[o + NIN] = a1;
        }
      }
    }
  }

  if (ny == 0) {
    __syncthreads();
    int rcount = lim - lm0; if (rcount > 128) rcount = 128;
    if (tid < rcount) {
      int r = list[chunk_off + lm0 + tid];
      if (SBh[tid] > 0.0f) {
        fpb[r] = SBp[tid];
      } else {
        int pos = atomicAdd(cntn, 1);
        listn[pos] = r;
      }
    }
  }
}

// ---------------- final ----------------
__global__ void k_final(const float* __restrict__ fpb, float* __restrict__ out) {
  int i = blockIdx.x * blockDim.x + threadIdx.x;
  if (i < NB) {
    out[i] = 1.0f / (1.0f + expf(-fpb[i]));
    out[NB + i] = 0.0f;
  }
}

extern "C" void kernel_launch(void* const* d_in, const int* in_sizes, int n_in,
                              void* d_out, int out_size, void* d_ws, size_t ws_size,
                              hipStream_t stream) {
  const float* x  = (const float*)d_in[0];
  const float* W1 = (const float*)d_in[1];
  const float* b1 = (const float*)d_in[2];
  const float* W2 = (const float*)d_in[3];
  const float* b2 = (const float*)d_in[4];
  const float* W3 = (const float*)d_in[5];
  const float* b3 = (const float*)d_in[6];
  float* out = (float*)d_out;

  char* p = (char*)d_ws;
  auto alloc = [&](size_t bytes) {
    char* r = p;
    p += (bytes + 255) & ~(size_t)255;
    return r;
  };
  f16* xm2  = (f16*)alloc((size_t)NB * 2 * NIN * 2);     // 80 MiB
  f16* W1T  = (f16*)alloc((size_t)NHID * 2 * NIN * 2);   // 5 MiB
  f16* W2T  = (f16*)alloc((size_t)NHID * 2 * NHID * 2);  // 16 MiB
  f16* W3T  = (f16*)alloc((size_t)NOUTP * 2 * NHID * 2); // 6 MiB
  float* fpb   = (float*)alloc((size_t)NB * 4);
  int* list0   = (int*)alloc((size_t)NB * 4);
  int* list1   = (int*)alloc((size_t)NB * 4);
  int* cnt     = (int*)alloc(32 * 4);

  size_t used = (size_t)(p - (char*)d_ws);
  size_t remain = (ws_size > used) ? (ws_size - used) : 0;
  long long chl = (long long)(remain / ((size_t)2 * 2 * NHID * 2)); // h1+h2 = 16384 B/row
  int CH = (int)(chl > NB ? NB : chl);
  CH &= ~127;
  if (CH > 8192) CH = 8192;   // grid = 1024 blocks = exactly 2 scheduling waves (512 slots)
  if (CH < 128) CH = 128;
  f16* h1 = (f16*)alloc((size_t)CH * 2 * NHID * 2);
  f16* h2 = (f16*)alloc((size_t)CH * 2 * NHID * 2);
  int nchunks = (NB + CH - 1) / CH;

  k_prepW<<<dim3(NIN / 32, NHID / 32), 256, 0, stream>>>(W1, W1T, NIN, NHID);
  k_prepW<<<dim3(NHID / 32, NHID / 32), 256, 0, stream>>>(W2, W2T, NHID, NHID);
  k_prepW<<<dim3(NHID / 32, NOUTP / 32), 256, 0, stream>>>(W3, W3T, NHID, NOUT);
  k_splitX<<<(NB * NH) / 256, 256, 0, stream>>>(x, xm2);
  k_init<<<(NB * NM) / 256, 256, 0, stream>>>(xm2, fpb, list0, cnt);

  for (int t = 0; t < ITERS; ++t) {
    const int* lc = (t & 1) ? list1 : list0;
    int* ln       = (t & 1) ? list0 : list1;
    const int* cc = cnt + t;
    int* cn       = cnt + t + 1;
    for (int c = 0; c < nchunks; ++c) {
      int off = c * CH;
      int rows = NB - off; if (rows > CH) rows = CH;
      int g1 = (CH / 128) * 16;
      k_l1<<<g1, 256, 0, stream>>>(xm2, W1T, b1, h1, lc, cc, off, rows);
      k_l2<<<g1, 256, 0, stream>>>(h1, W2T, b2, h2, cc, off, rows);
      int g3 = (CH / 128) * 6;
      k_l3<<<g3, 256, 0, stream>>>(h2, W3T, b3, xm2, fpb, lc, ln, cc, cn, off, rows);
    }
  }
  k_final<<<NB / 256, 256, 0, stream>>>(fpb, out);
}